// Round 1
// baseline (71.559 us; speedup 1.0000x reference)
//
#include <hip/hip_runtime.h>

// Shapes fixed by the reference: bs=4, n=10, H=W=256.
constexpr int kN   = 10;        // planes
constexpr int kHW  = 256 * 256;
constexpr int kBS  = 4;
constexpr int kPix = 4;         // pixels per thread (float4 loads, 16 B/lane)

// 4 pixels per thread via float4; per-pixel arithmetic is BIT-IDENTICAL to
// the verified scalar kernel (absmax == 0.0 contract — preserve it):
//  * sum over planes: left-associative sequential adds (prefix-shared,
//    SAME association as the reference fold).
//  * x/10 and x/9: (float)((double)x * RN(1/10 or 1/9)) — proven identical
//    to correctly-rounded fp32 division for all inputs (see R1/R2 notes:
//    f64 product rel-err <= 2.3e-16 vs >= ~8e-10 distance to any fp32
//    rounding midpoint for m*2^e/10 and /9).
//  * (v-mean)^2: separate sub/mul/add under fp contract(off) — no FMA.
//  * sqrtf: HIP default correctly-rounded fp32 sqrt.
//  * argmin: strict <, first occurrence.
// DO NOT introduce incremental-sum recurrences, var-based argmin, or FMA
// contraction: an argmin tie-flip costs up to 2*blur/n ~ 0.2 vs thr 3.8e-2.
//
// All inner loops (j, i, px) are fully unrolled so every array index is a
// compile-time constant — runtime-indexed ext-vector/arrays would spill to
// scratch (localMem) and cost ~5x.
__global__ __launch_bounds__(256) void distreg_kernel(
    const float* __restrict__ s1, const float* __restrict__ blur,
    float* __restrict__ out) {
  #pragma clang fp contract(off)
  const int t = blockIdx.x * blockDim.x + threadIdx.x;  // quad id
  const int g = t * kPix;                               // first pixel of quad
  const int b = g >> 16;        // kHW == 65536
  const int r = g & (kHW - 1);  // multiple of 4 -> float4 aligned

  const long base = (long)b * kN * kHW + r;

  // Stage lo/hi for 4 pixels: 20 float4 loads instead of 80 scalar loads.
  float lo[kN][kPix], hi[kN][kPix];
  #pragma unroll
  for (int j = 0; j < kN; ++j) {
    const float4 s  = *reinterpret_cast<const float4*>(s1   + base + (long)j * kHW);
    const float4 bl = *reinterpret_cast<const float4*>(blur + base + (long)j * kHW);
    lo[j][0] = s.x - bl.x;  hi[j][0] = s.x + bl.x;
    lo[j][1] = s.y - bl.y;  hi[j][1] = s.y + bl.y;
    lo[j][2] = s.z - bl.z;  hi[j][2] = s.z + bl.z;
    lo[j][3] = s.w - bl.w;  hi[j][3] = s.w + bl.w;
  }

  float res[kPix];
  #pragma unroll
  for (int px = 0; px < kPix; ++px) {
    float best_sd   = INFINITY;
    float best_mean = 0.0f;
    float p = 0.0f;             // prefix: hi[0] + ... + hi[i-1], left-assoc
    #pragma unroll
    for (int i = 0; i <= kN; ++i) {
      // sum_i = ((p + lo[i]) + lo[i+1]) + ... — same association as reference.
      float sum = p;
      #pragma unroll
      for (int j = 0; j < kN; ++j) if (j >= i) sum = sum + lo[j][px];
      const float mean = (float)((double)sum * 0.1);      // == sum / 10.0f

      float sq = 0.0f;
      #pragma unroll
      for (int j = 0; j < kN; ++j) {
        const float v  = (j < i) ? hi[j][px] : lo[j][px]; // static select
        const float x  = v - mean;
        const float xx = x * x;   // contract(off): stays a separate mul
        sq = sq + xx;
      }
      const float var = (float)((double)sq * (1.0 / 9.0)); // == sq / 9.0f
      const float sd  = sqrtf(var);

      if (sd < best_sd) { best_sd = sd; best_mean = mean; } // first occurrence
      if (i < kN) p = p + hi[i][px];
    }
    res[px] = best_mean;
  }

  float4 o;
  o.x = res[0]; o.y = res[1]; o.z = res[2]; o.w = res[3];
  *reinterpret_cast<float4*>(out + (long)b * kHW + r) = o;
}

extern "C" void kernel_launch(void* const* d_in, const int* in_sizes, int n_in,
                              void* d_out, int out_size, void* d_ws, size_t ws_size,
                              hipStream_t stream) {
  const float* s1   = (const float*)d_in[0];
  const float* blur = (const float*)d_in[1];
  float* out = (float*)d_out;

  const int total = kBS * kHW;                 // 1,048,576 pixels
  const int block = 256;
  const int grid  = total / (block * kPix);    // 1024 blocks, 4 quads each
  distreg_kernel<<<grid, block, 0, stream>>>(s1, blur, out);
}

// Round 2
// 71.361 us; speedup vs baseline: 1.0028x; 1.0028x over previous
//
#include <hip/hip_runtime.h>

// Shapes fixed by the reference: bs=4, n=10, H=W=256.
constexpr int kN   = 10;        // planes
constexpr int kHW  = 256 * 256;
constexpr int kBS  = 4;
constexpr int kPix = 2;         // pixels per thread (float2 loads, 8 B/lane)

// 2 pixels per thread via float2; per-pixel arithmetic is BIT-IDENTICAL to
// the verified scalar kernel (absmax == 0.0 contract — preserve it):
//  * sum over planes: left-associative sequential adds (prefix-shared,
//    SAME association as the reference fold).
//  * x/10 and x/9: (float)((double)x * RN(1/10 or 1/9)) — proven identical
//    to correctly-rounded fp32 division for all inputs (f64 product rel-err
//    <= 2.3e-16 vs >= ~8e-10 distance to any fp32 rounding midpoint for
//    m*2^e/10 and /9).
//  * (v-mean)^2: separate sub/mul/add under fp contract(off) — no FMA.
//  * sqrtf: HIP default correctly-rounded fp32 sqrt.
//  * argmin: strict <, first occurrence (bootstrapped from i=0; the i=0
//    branch is taken unconditionally, preserving first-occurrence).
// DO NOT introduce incremental-sum recurrences, var-based argmin, or FMA
// contraction: an argmin tie-flip costs up to 2*blur/n ~ 0.2 vs thr 3.8e-2.
//
// __launch_bounds__(256,4): min 4 waves/EU -> VGPR cap 128, guaranteeing
// >=4 waves/SIMD to hide the serial sq-accumulation chains; 2 px/thread
// gives 2 independent chains of ILP on top. All loops fully unrolled so
// every array index is compile-time constant (runtime-indexed arrays
// would spill to scratch).
__global__ __launch_bounds__(256, 4) void distreg_kernel(
    const float* __restrict__ s1, const float* __restrict__ blur,
    float* __restrict__ out) {
  #pragma clang fp contract(off)
  const int t = blockIdx.x * blockDim.x + threadIdx.x;  // pair id
  const int g = t * kPix;                               // first pixel of pair
  const int b = g >> 16;        // kHW == 65536
  const int r = g & (kHW - 1);  // multiple of 2 -> float2 aligned

  const long base = (long)b * kN * kHW + r;

  // Stage lo/hi for 2 pixels: 20 float2 loads instead of 40 scalar loads.
  float lo[kN][kPix], hi[kN][kPix];
  #pragma unroll
  for (int j = 0; j < kN; ++j) {
    const float2 s  = *reinterpret_cast<const float2*>(s1   + base + (long)j * kHW);
    const float2 bl = *reinterpret_cast<const float2*>(blur + base + (long)j * kHW);
    lo[j][0] = s.x - bl.x;  hi[j][0] = s.x + bl.x;
    lo[j][1] = s.y - bl.y;  hi[j][1] = s.y + bl.y;
  }

  float res[kPix];
  #pragma unroll
  for (int px = 0; px < kPix; ++px) {
    float best_sd;
    float best_mean;
    float p = 0.0f;             // prefix: hi[0] + ... + hi[i-1], left-assoc
    #pragma unroll
    for (int i = 0; i <= kN; ++i) {
      // sum_i = ((p + lo[i]) + lo[i+1]) + ... — same association as reference.
      float sum = p;
      #pragma unroll
      for (int j = 0; j < kN; ++j) if (j >= i) sum = sum + lo[j][px];
      const float mean = (float)((double)sum * 0.1);      // == sum / 10.0f

      float sq = 0.0f;
      #pragma unroll
      for (int j = 0; j < kN; ++j) {
        const float v  = (j < i) ? hi[j][px] : lo[j][px]; // static select
        const float x  = v - mean;
        const float xx = x * x;   // contract(off): stays a separate mul
        sq = sq + xx;
      }
      const float var = (float)((double)sq * (1.0 / 9.0)); // == sq / 9.0f
      const float sd  = sqrtf(var);

      if (i == 0) {                       // unconditional first entry
        best_sd = sd; best_mean = mean;
      } else if (sd < best_sd) {          // strict <: first occurrence wins
        best_sd = sd; best_mean = mean;
      }
      if (i < kN) p = p + hi[i][px];
    }
    res[px] = best_mean;
  }

  float2 o;
  o.x = res[0]; o.y = res[1];
  *reinterpret_cast<float2*>(out + (long)b * kHW + r) = o;
}

extern "C" void kernel_launch(void* const* d_in, const int* in_sizes, int n_in,
                              void* d_out, int out_size, void* d_ws, size_t ws_size,
                              hipStream_t stream) {
  const float* s1   = (const float*)d_in[0];
  const float* blur = (const float*)d_in[1];
  float* out = (float*)d_out;

  const int total = kBS * kHW;                 // 1,048,576 pixels
  const int block = 256;
  const int grid  = total / (block * kPix);    // 2048 blocks
  distreg_kernel<<<grid, block, 0, stream>>>(s1, blur, out);
}